// Round 5
// baseline (1282.902 us; speedup 1.0000x reference)
//
#include <hip/hip_runtime.h>
#include <hip/hip_bf16.h>

#define B_ 2048
#define S_ 71
#define D_ 768
#define H_ 4
#define DH_ 192
#define TD_ 2304            // 3*D
#define M_ (B_ * S_)        // 145408 = 568*256
#define TEXT_ 35
#define NKT 12              // 768 / 64 K-tiles

typedef unsigned short u16;
typedef unsigned int u32;
typedef __attribute__((ext_vector_type(4))) float f32x4;
typedef __attribute__((ext_vector_type(8))) short bf16x8;

__device__ __forceinline__ u16 f2bf(float f) {
  u32 u = __float_as_uint(f);
  u32 r = (u + 0x7FFFu + ((u >> 16) & 1u)) >> 16;  // RNE
  return (u16)r;
}
__device__ __forceinline__ float bf2f(u16 x) {
  return __uint_as_float(((u32)x) << 16);
}

typedef __attribute__((address_space(1))) const unsigned int GASU;
typedef __attribute__((address_space(3))) unsigned int LASU;
__device__ __forceinline__ void gload16(const void* g, void* l) {
  __builtin_amdgcn_global_load_lds((GASU*)g, (LASU*)l, 16, 0, 0);
}

#define PHASE_BAR() do { __builtin_amdgcn_s_barrier(); asm volatile("" ::: "memory"); } while (0)

// ---------------------------------------------------------------------------
// fp32 -> bf16 elementwise, 8 elems/thread, exact grid
__global__ __launch_bounds__(256) void k_cvt_bf16(const float* __restrict__ in,
                                                  u16* __restrict__ out, int n8) {
  int idx = blockIdx.x * 256 + threadIdx.x;
  if (idx >= n8) return;
  const float4* p = (const float4*)(in + (size_t)idx * 8);
  float4 a = p[0], b = p[1];
  uint4 o;
  o.x = (u32)f2bf(a.x) | ((u32)f2bf(a.y) << 16);
  o.y = (u32)f2bf(a.z) | ((u32)f2bf(a.w) << 16);
  o.z = (u32)f2bf(b.x) | ((u32)f2bf(b.y) << 16);
  o.w = (u32)f2bf(b.z) | ((u32)f2bf(b.w) << 16);
  *(uint4*)(out + (size_t)idx * 8) = o;
}

// ---------------------------------------------------------------------------
// w_out [e][d] -> w_outT [d][e]  (768x768 fp32, tiny)
__global__ void k_transpose768(const float* __restrict__ in, float* __restrict__ out) {
  int idx = blockIdx.x * 256 + threadIdx.x;
  int e = idx / 768, d = idx % 768;
  out[(size_t)d * 768 + e] = in[idx];
}

// ---------------------------------------------------------------------------
// GEMM: C[M,2304] = A[M,768](bf16) * Bw[2304,768](bf16 n-major), bias + phi
// epilogue. 256x256 tile, BK=64, 8 waves (2Mx4N), 512 thr, 128 KiB LDS
// (2 K-tile dbuf). 2-deep staging: tile T+2's loads issued at ph2 of iter T
// into the CURRENT buffer (last read of cur is at ph1; barrier between);
// end-of-iter wait is counted vmcnt(8) -> only tile T+1's loads drained,
// T+2's stay in flight. Issue->wait distance ~6 phases >= HBM latency.
// chunk^(row&7) 16B XOR swizzle on source+read. Non-temporal C stores.
__global__ __launch_bounds__(512, 2) void k_gemm_qkv(
    const u16* __restrict__ Abf,  // [M_,768] bf16
    const u16* __restrict__ Bw,   // [2304,768] bf16 (n-major)
    const float* __restrict__ bias, // [2304]
    u16* __restrict__ C)            // [M_,2304] bf16, phi on cols<1536
{
  // layout (u16 units): buf*32768 + op*16384 + half*8192 ; half = [128][64]
  __shared__ u16 sm[65536];   // 128 KiB
  int t = threadIdx.x;
  int lane = t & 63, wid = t >> 6;
  int wr = wid >> 2, wc = wid & 3;     // 2 x 4 wave grid
  int lr = lane & 15;
  int g4 = lane >> 4;                  // 0..3 (K granule within kk)

  // XCD-bijective swizzle: nwg = 5112 = 8 * 639; bn inner -> A-panel L2 reuse
  int swz = (blockIdx.x & 7) * 639 + (blockIdx.x >> 3);
  int bm = swz / 9, bn = swz % 9;
  const size_t arow0 = (size_t)bm * 256;
  const int bcol0 = bn * 256;

  // ---- staging descriptors (loop-invariant) --------------------------------
  // chunk ci = w*512 + t -> row = ci>>3, phys granule kg = (ci&7)^(row&7)
  int voff[2][2], lba[2][2];
#pragma unroll
  for (int half = 0; half < 2; ++half)
#pragma unroll
    for (int w = 0; w < 2; ++w) {
      int ci = w * 512 + t;
      int row = ci >> 3;
      int kg = (ci & 7) ^ (row & 7);
      voff[half][w] = (half * 128 + row) * 768 + kg * 8;   // u16 units
      lba[half][w] = half * 8192 + w * 4096 + wid * 512;   // wave-uniform LDS base
    }
  const u16* baseA = Abf + arow0 * 768;
  const u16* baseB = Bw + (size_t)bcol0 * 768;

#define STAGE_A(nb, kc) do { \
  gload16(baseA + voff[0][0] + (kc), &sm[(nb) + lba[0][0]]); \
  gload16(baseA + voff[0][1] + (kc), &sm[(nb) + lba[0][1]]); \
  gload16(baseA + voff[1][0] + (kc), &sm[(nb) + lba[1][0]]); \
  gload16(baseA + voff[1][1] + (kc), &sm[(nb) + lba[1][1]]); \
} while (0)
#define STAGE_B(nb, kc) do { \
  gload16(baseB + voff[0][0] + (kc), &sm[(nb) + 16384 + lba[0][0]]); \
  gload16(baseB + voff[0][1] + (kc), &sm[(nb) + 16384 + lba[0][1]]); \
  gload16(baseB + voff[1][0] + (kc), &sm[(nb) + 16384 + lba[1][0]]); \
  gload16(baseB + voff[1][1] + (kc), &sm[(nb) + 16384 + lba[1][1]]); \
} while (0)

  // ---- fragment read offsets (swizzled) ------------------------------------
  int gx0 = g4 ^ (lr & 7);             // kk=0 granule; kk=1 -> gx0^4
  int abase = wr * 8192 + lr * 64;                      // + mi*1024 + gsw*8
  int bbase = 16384 + (wc >> 1) * 8192 + (wc & 1) * 4096 + lr * 64; // + ni*1024

  f32x4 acc[8][4] = {};
  bf16x8 a0_[4][2], a1_[4][2], b0_[2][2], b1_[2][2];

#define RDA(bufb, mi, gsw) (*(const bf16x8*)(&sm[(bufb) + abase + (mi) * 1024 + (gsw) * 8]))
#define RDB(bufb, ni, gsw) (*(const bf16x8*)(&sm[(bufb) + bbase + (ni) * 1024 + (gsw) * 8]))
#define READ_A1(bufb) do { \
  _Pragma("unroll") for (int mi = 0; mi < 4; ++mi) { \
    a1_[mi][0] = RDA(bufb, mi + 4, gx0); a1_[mi][1] = RDA(bufb, mi + 4, gx0 ^ 4); } \
} while (0)
#define READ_A0(bufb) do { \
  _Pragma("unroll") for (int mi = 0; mi < 4; ++mi) { \
    a0_[mi][0] = RDA(bufb, mi, gx0); a0_[mi][1] = RDA(bufb, mi, gx0 ^ 4); } \
} while (0)
#define READ_B0(bufb) do { \
  _Pragma("unroll") for (int ni = 0; ni < 2; ++ni) { \
    b0_[ni][0] = RDB(bufb, ni, gx0); b0_[ni][1] = RDB(bufb, ni, gx0 ^ 4); } \
} while (0)
#define READ_B1(bufb) do { \
  _Pragma("unroll") for (int ni = 0; ni < 2; ++ni) { \
    b1_[ni][0] = RDB(bufb, ni + 2, gx0); b1_[ni][1] = RDB(bufb, ni + 2, gx0 ^ 4); } \
} while (0)
#define MFMA_Q(AF, BF, MO, NO) do { \
  __builtin_amdgcn_s_setprio(1); \
  _Pragma("unroll") for (int mi = 0; mi < 4; ++mi) \
  _Pragma("unroll") for (int ni = 0; ni < 2; ++ni) \
  _Pragma("unroll") for (int kk = 0; kk < 2; ++kk) \
    acc[mi + (MO)][ni + (NO)] = __builtin_amdgcn_mfma_f32_16x16x32_bf16( \
        AF[mi][kk], BF[ni][kk], acc[mi + (MO)][ni + (NO)], 0, 0, 0); \
  __builtin_amdgcn_s_setprio(0); \
} while (0)

  // prologue: stage tiles 0 and 1; wait only for tile 0 (vmcnt(8) leaves
  // tile 1's 8 loads in flight); pre-read tile 0's Q0 operands.
  STAGE_A(0, 0); STAGE_B(0, 0);
  STAGE_A(32768, 64); STAGE_B(32768, 64);
  asm volatile("s_waitcnt vmcnt(8)" ::: "memory");
  PHASE_BAR();
  READ_A1(0); READ_B0(0);

  for (int T = 0; T < NKT; ++T) {
    int cur = (T & 1) * 32768;
    int nxt = 32768 - cur;
    // ph0: Q0 = (mh1, B0); read B1(cur)
    MFMA_Q(a1_, b0_, 4, 0);
    READ_B1(cur);
    PHASE_BAR();
    // ph1: Q1 = (mh1, B1); read A0(cur) — last reads of cur buffer
    MFMA_Q(a1_, b1_, 4, 2);
    READ_A0(cur);
    PHASE_BAR();
    // ph2: Q2 = (mh0, B1); stage tile T+2 into cur (WAR-safe: barrier above)
    MFMA_Q(a0_, b1_, 0, 2);
    if (T <= NKT - 3) { STAGE_A(cur, (T + 2) * 64); STAGE_B(cur, (T + 2) * 64); }
    PHASE_BAR();
    // ph3: Q3 = (mh0, B0) — all operands held, pure MFMA
    MFMA_Q(a0_, b0_, 0, 0);
    if (T < NKT - 1) {
      // need tile T+1 landed; newest 8 loads (tile T+2) may stay in flight
      if (T <= NKT - 3) asm volatile("s_waitcnt vmcnt(8)" ::: "memory");
      else              asm volatile("s_waitcnt vmcnt(0)" ::: "memory");
      PHASE_BAR();
      READ_A1(nxt); READ_B0(nxt);      // tile T+1 Q0 operands
    }
  }

  // epilogue: bias + phi, non-temporal bf16 stores (don't evict A/B panels)
  int rb = g4 * 4;
#pragma unroll
  for (int mi = 0; mi < 8; ++mi) {
#pragma unroll
    for (int ni = 0; ni < 4; ++ni) {
      int col = bcol0 + wc * 64 + ni * 16 + lr;
      float bb = bias[col];
#pragma unroll
      for (int i = 0; i < 4; ++i) {
        size_t row = arow0 + wr * 128 + mi * 16 + rb + i;
        float v = acc[mi][ni][i] + bb;
        if (col < 1536) v = (v > 0.0f) ? (v + 1.0f) : __expf(v);
        __builtin_nontemporal_store(f2bf(v), &C[row * TD_ + col]);
      }
    }
  }
#undef RDA
#undef RDB
}

// ---------------------------------------------------------------------------
// Attention core, one block per (b,h). Never materializes kv[192][192].
#define ALD 196  // LDS stride for 192-wide bf16 rows

__global__ __launch_bounds__(256) void k_attn(
    const u16* __restrict__ qkv,  // [M_,2304] bf16
    float* __restrict__ mt, float* __restrict__ mi)  // [B_,768] fp32
{
  __shared__ u16 qs[S_ * ALD];
  __shared__ u16 ks2[S_ * ALD];
  __shared__ float z[DH_], wt[S_], wi[S_], qt[DH_], qi[DH_], at[S_], ai[S_];
  int t = threadIdx.x;
  int b = blockIdx.x >> 2, h = blockIdx.x & 3;
  size_t base = (size_t)b * S_ * TD_;
  int qoff = h * DH_, koff = 768 + h * DH_, voff = 1536 + h * DH_;

  for (int idx = t; idx < S_ * 48; idx += 256) {
    int s = idx / 48, c = (idx % 48) * 4;
    *(ushort4*)(&qs[s * ALD + c])  = *(const ushort4*)(&qkv[base + (size_t)s * TD_ + qoff + c]);
    *(ushort4*)(&ks2[s * ALD + c]) = *(const ushort4*)(&qkv[base + (size_t)s * TD_ + koff + c]);
  }
  __syncthreads();
  if (t < DH_) {
    float a = 0;
    for (int s = 0; s < S_; ++s) a += bf2f(ks2[s * ALD + t]);
    z[t] = a;
  }
  __syncthreads();
  if (t < S_) {
    float a = 0;
    for (int d = 0; d < DH_; ++d) a += bf2f(qs[t * ALD + d]) * z[d];
    float den = a + 1e-6f;
    wt[t] = (t < TEXT_) ? 1.0f / (35.0f * den) : 0.0f;
    wi[t] = (t >= TEXT_) ? 1.0f / (36.0f * den) : 0.0f;
  }
  __syncthreads();
  if (t < DH_) {
    float aT = 0, aI = 0;
    for (int s = 0; s < S_; ++s) {
      float qv = bf2f(qs[s * ALD + t]);
      aT += qv * wt[s]; aI += qv * wi[s];
    }
    qt[t] = aT; qi[t] = aI;
  }
  __syncthreads();
  if (t < S_) {
    float aT = 0, aI = 0;
    for (int d = 0; d < DH_; ++d) {
      float kv = bf2f(ks2[t * ALD + d]);
      aT += kv * qt[d]; aI += kv * qi[d];
    }
    at[t] = aT; ai[t] = aI;
  }
  __syncthreads();
  if (t < DH_) {
    float aT = 0, aI = 0;
    for (int s = 0; s < S_; ++s) {
      float vv = bf2f(qkv[base + (size_t)s * TD_ + voff + t]);
      aT += at[s] * vv; aI += ai[s] * vv;
    }
    mt[(size_t)b * D_ + qoff + t] = aT;
    mi[(size_t)b * D_ + qoff + t] = aI;
  }
}

// ---------------------------------------------------------------------------
// Final head: f = m @ w_out^T + b_out ; r = tanh(f) ; cosine similarity.
// GFIN=4: 512 blocks -> 2 waves/SIMD (GFIN=8's 256 blocks was latency-bound).
#define GFIN 4
__global__ __launch_bounds__(256) void k_final(
    const float* __restrict__ mt, const float* __restrict__ mi,
    const float* __restrict__ wT,   // [768,768] = w_out transposed [d][e]
    const float* __restrict__ bout, // [768]
    float* __restrict__ out)        // [B_]
{
  __shared__ float mts[GFIN][768], mis[GFIN][768];
  __shared__ float red[3][4];
  int t = threadIdx.x, b0 = blockIdx.x * GFIN;
  for (int i = t; i < GFIN * 768; i += 256) {
    int g = i / 768, d = i % 768;
    mts[g][d] = mt[(size_t)(b0 + g) * 768 + d];
    mis[g][d] = mi[(size_t)(b0 + g) * 768 + d];
  }
  __syncthreads();
  float aT[GFIN][3] = {}, aI[GFIN][3] = {};
  for (int d = 0; d < 768; ++d) {
    const float* wrow = wT + (size_t)d * 768 + t;
    float w0 = wrow[0], w1 = wrow[256], w2 = wrow[512];
#pragma unroll
    for (int g = 0; g < GFIN; ++g) {
      float m1 = mts[g][d], m2 = mis[g][d];
      aT[g][0] += m1 * w0; aT[g][1] += m1 * w1; aT[g][2] += m1 * w2;
      aI[g][0] += m2 * w0; aI[g][1] += m2 * w1; aI[g][2] += m2 * w2;
    }
  }
  int lane = t & 63, wid = t >> 6;
  for (int g = 0; g < GFIN; ++g) {
    float st = 0, si = 0, sd = 0;
#pragma unroll
    for (int j = 0; j < 3; ++j) {
      float bo = bout[t + j * 256];
      float rt = tanhf(aT[g][j] + bo);
      float ri = tanhf(aI[g][j] + bo);
      st += rt * rt; si += ri * ri; sd += rt * ri;
    }
#pragma unroll
    for (int off = 32; off >= 1; off >>= 1) {
      st += __shfl_down(st, off);
      si += __shfl_down(si, off);
      sd += __shfl_down(sd, off);
    }
    __syncthreads();
    if (lane == 0) { red[0][wid] = st; red[1][wid] = si; red[2][wid] = sd; }
    __syncthreads();
    if (t == 0) {
      float S1 = red[0][0] + red[0][1] + red[0][2] + red[0][3];
      float S2 = red[1][0] + red[1][1] + red[1][2] + red[1][3];
      float S3 = red[2][0] + red[2][1] + red[2][2] + red[2][3];
      out[b0 + g] = S3 / (fmaxf(sqrtf(S1), 1e-8f) * fmaxf(sqrtf(S2), 1e-8f));
    }
  }
}

// ---------------------------------------------------------------------------
extern "C" void kernel_launch(void* const* d_in, const int* in_sizes, int n_in,
                              void* d_out, int out_size, void* d_ws, size_t ws_size,
                              hipStream_t stream) {
  const float* features = (const float*)d_in[0];
  // d_in[1] = attention_mask (unused by forward)
  const float* w_qkv = (const float*)d_in[2];
  const float* b_qkv = (const float*)d_in[3];
  const float* w_out = (const float*)d_in[4];
  const float* b_out = (const float*)d_in[5];
  float* out = (float*)d_out;

  char* ws = (char*)d_ws;
  size_t off = 0;
  auto alloc = [&](size_t bytes) {
    void* p = ws + off;
    off += (bytes + 255) & ~(size_t)255;
    return p;
  };
  u16* qkv  = (u16*)alloc((size_t)M_ * TD_ * 2);   // 670 MB
  u16* Abf  = (u16*)alloc((size_t)M_ * D_ * 2);    // 223 MB
  u16* Wbf  = (u16*)alloc((size_t)TD_ * D_ * 2);   // 3.5 MB
  float* wT = (float*)alloc((size_t)D_ * D_ * 4);  // 2.4 MB
  float* mt = (float*)alloc((size_t)B_ * D_ * 4);  // 6.3 MB
  float* mi = (float*)alloc((size_t)B_ * D_ * 4);  // 6.3 MB
  (void)ws_size;

  hipLaunchKernelGGL(k_cvt_bf16, dim3((M_ * D_ / 8 + 255) / 256), dim3(256), 0, stream,
                     features, Abf, M_ * D_ / 8);
  hipLaunchKernelGGL(k_cvt_bf16, dim3((TD_ * D_ / 8 + 255) / 256), dim3(256), 0, stream,
                     w_qkv, Wbf, TD_ * D_ / 8);
  hipLaunchKernelGGL(k_transpose768, dim3(2304), dim3(256), 0, stream, w_out, wT);

  hipLaunchKernelGGL(k_gemm_qkv, dim3(568 * 9), dim3(512), 0, stream,
                     Abf, Wbf, b_qkv, qkv);
  hipLaunchKernelGGL(k_attn, dim3(B_ * H_), dim3(256), 0, stream, qkv, mt, mi);
  hipLaunchKernelGGL(k_final, dim3(B_ / GFIN), dim3(256), 0, stream, mt, mi, wT, b_out, out);
}

// Round 6
// 1148.823 us; speedup vs baseline: 1.1167x; 1.1167x over previous
//
#include <hip/hip_runtime.h>
#include <hip/hip_bf16.h>

#define B_ 2048
#define S_ 71
#define D_ 768
#define H_ 4
#define DH_ 192
#define TD_ 2304            // 3*D
#define M_ (B_ * S_)        // 145408 = 568*256
#define TEXT_ 35
#define NKT 12              // 768 / 64 K-tiles

typedef unsigned short u16;
typedef unsigned int u32;
typedef __attribute__((ext_vector_type(4))) float f32x4;
typedef __attribute__((ext_vector_type(8))) short bf16x8;

__device__ __forceinline__ u16 f2bf(float f) {
  u32 u = __float_as_uint(f);
  u32 r = (u + 0x7FFFu + ((u >> 16) & 1u)) >> 16;  // RNE
  return (u16)r;
}
__device__ __forceinline__ float bf2f(u16 x) {
  return __uint_as_float(((u32)x) << 16);
}

typedef __attribute__((address_space(1))) const unsigned int GASU;
typedef __attribute__((address_space(3))) unsigned int LASU;
__device__ __forceinline__ void gload16(const void* g, void* l) {
  __builtin_amdgcn_global_load_lds((GASU*)g, (LASU*)l, 16, 0, 0);
}

#define PHASE_BAR() do { __builtin_amdgcn_s_barrier(); asm volatile("" ::: "memory"); } while (0)

// ---------------------------------------------------------------------------
// fp32 -> bf16 elementwise, 8 elems/thread, exact grid
__global__ __launch_bounds__(256) void k_cvt_bf16(const float* __restrict__ in,
                                                  u16* __restrict__ out, int n8) {
  int idx = blockIdx.x * 256 + threadIdx.x;
  if (idx >= n8) return;
  const float4* p = (const float4*)(in + (size_t)idx * 8);
  float4 a = p[0], b = p[1];
  uint4 o;
  o.x = (u32)f2bf(a.x) | ((u32)f2bf(a.y) << 16);
  o.y = (u32)f2bf(a.z) | ((u32)f2bf(a.w) << 16);
  o.z = (u32)f2bf(b.x) | ((u32)f2bf(b.y) << 16);
  o.w = (u32)f2bf(b.z) | ((u32)f2bf(b.w) << 16);
  *(uint4*)(out + (size_t)idx * 8) = o;
}

// ---------------------------------------------------------------------------
// w_out [e][d] -> w_outT [d][e]  (768x768 fp32, tiny)
__global__ void k_transpose768(const float* __restrict__ in, float* __restrict__ out) {
  int idx = blockIdx.x * 256 + threadIdx.x;
  int e = idx / 768, d = idx % 768;
  out[(size_t)d * 768 + e] = in[idx];
}

// ---------------------------------------------------------------------------
// GEMM: C[M,2304] = A[M,768](bf16) * Bw[2304,768](bf16 n-major), bias + phi
// epilogue. 256x256 tile, BK=64, 8 waves (2Mx4N), 512 thr, 128 KiB LDS
// (2 K-tile dbuf). 2-deep staging: tile T+2's loads issued at ph2 of iter T
// into the CURRENT buffer (last read of cur is at ph1; barrier between);
// end-of-iter wait is counted vmcnt(8) -> only tile T+1's loads drained,
// T+2's stay in flight. Issue->wait distance ~6 phases >= HBM latency.
// chunk^(row&7) 16B XOR swizzle on source+read. NORMAL C stores (L2 merges
// partial lines; nontemporal caused 2.2x write amplification — round 5).
__global__ __launch_bounds__(512, 2) void k_gemm_qkv(
    const u16* __restrict__ Abf,  // [M_,768] bf16
    const u16* __restrict__ Bw,   // [2304,768] bf16 (n-major)
    const float* __restrict__ bias, // [2304]
    u16* __restrict__ C)            // [M_,2304] bf16, phi on cols<1536
{
  // layout (u16 units): buf*32768 + op*16384 + half*8192 ; half = [128][64]
  __shared__ u16 sm[65536];   // 128 KiB
  int t = threadIdx.x;
  int lane = t & 63, wid = t >> 6;
  int wr = wid >> 2, wc = wid & 3;     // 2 x 4 wave grid
  int lr = lane & 15;
  int g4 = lane >> 4;                  // 0..3 (K granule within kk)

  // XCD-bijective swizzle: nwg = 5112 = 8 * 639; bn inner -> A-panel L2 reuse
  int swz = (blockIdx.x & 7) * 639 + (blockIdx.x >> 3);
  int bm = swz / 9, bn = swz % 9;
  const size_t arow0 = (size_t)bm * 256;
  const int bcol0 = bn * 256;

  // ---- staging descriptors (loop-invariant) --------------------------------
  // chunk ci = w*512 + t -> row = ci>>3, phys granule kg = (ci&7)^(row&7)
  int voff[2][2], lba[2][2];
#pragma unroll
  for (int half = 0; half < 2; ++half)
#pragma unroll
    for (int w = 0; w < 2; ++w) {
      int ci = w * 512 + t;
      int row = ci >> 3;
      int kg = (ci & 7) ^ (row & 7);
      voff[half][w] = (half * 128 + row) * 768 + kg * 8;   // u16 units
      lba[half][w] = half * 8192 + w * 4096 + wid * 512;   // wave-uniform LDS base
    }
  const u16* baseA = Abf + arow0 * 768;
  const u16* baseB = Bw + (size_t)bcol0 * 768;

#define STAGE_A(nb, kc) do { \
  gload16(baseA + voff[0][0] + (kc), &sm[(nb) + lba[0][0]]); \
  gload16(baseA + voff[0][1] + (kc), &sm[(nb) + lba[0][1]]); \
  gload16(baseA + voff[1][0] + (kc), &sm[(nb) + lba[1][0]]); \
  gload16(baseA + voff[1][1] + (kc), &sm[(nb) + lba[1][1]]); \
} while (0)
#define STAGE_B(nb, kc) do { \
  gload16(baseB + voff[0][0] + (kc), &sm[(nb) + 16384 + lba[0][0]]); \
  gload16(baseB + voff[0][1] + (kc), &sm[(nb) + 16384 + lba[0][1]]); \
  gload16(baseB + voff[1][0] + (kc), &sm[(nb) + 16384 + lba[1][0]]); \
  gload16(baseB + voff[1][1] + (kc), &sm[(nb) + 16384 + lba[1][1]]); \
} while (0)

  // ---- fragment read offsets (swizzled) ------------------------------------
  int gx0 = g4 ^ (lr & 7);             // kk=0 granule; kk=1 -> gx0^4
  int abase = wr * 8192 + lr * 64;                      // + mi*1024 + gsw*8
  int bbase = 16384 + (wc >> 1) * 8192 + (wc & 1) * 4096 + lr * 64; // + ni*1024

  f32x4 acc[8][4] = {};
  bf16x8 a0_[4][2], a1_[4][2], b0_[2][2], b1_[2][2];

#define RDA(bufb, mi, gsw) (*(const bf16x8*)(&sm[(bufb) + abase + (mi) * 1024 + (gsw) * 8]))
#define RDB(bufb, ni, gsw) (*(const bf16x8*)(&sm[(bufb) + bbase + (ni) * 1024 + (gsw) * 8]))
#define READ_A1(bufb) do { \
  _Pragma("unroll") for (int mi = 0; mi < 4; ++mi) { \
    a1_[mi][0] = RDA(bufb, mi + 4, gx0); a1_[mi][1] = RDA(bufb, mi + 4, gx0 ^ 4); } \
} while (0)
#define READ_A0(bufb) do { \
  _Pragma("unroll") for (int mi = 0; mi < 4; ++mi) { \
    a0_[mi][0] = RDA(bufb, mi, gx0); a0_[mi][1] = RDA(bufb, mi, gx0 ^ 4); } \
} while (0)
#define READ_B0(bufb) do { \
  _Pragma("unroll") for (int ni = 0; ni < 2; ++ni) { \
    b0_[ni][0] = RDB(bufb, ni, gx0); b0_[ni][1] = RDB(bufb, ni, gx0 ^ 4); } \
} while (0)
#define READ_B1(bufb) do { \
  _Pragma("unroll") for (int ni = 0; ni < 2; ++ni) { \
    b1_[ni][0] = RDB(bufb, ni + 2, gx0); b1_[ni][1] = RDB(bufb, ni + 2, gx0 ^ 4); } \
} while (0)
#define MFMA_Q(AF, BF, MO, NO) do { \
  __builtin_amdgcn_s_setprio(1); \
  _Pragma("unroll") for (int mi = 0; mi < 4; ++mi) \
  _Pragma("unroll") for (int ni = 0; ni < 2; ++ni) \
  _Pragma("unroll") for (int kk = 0; kk < 2; ++kk) \
    acc[mi + (MO)][ni + (NO)] = __builtin_amdgcn_mfma_f32_16x16x32_bf16( \
        AF[mi][kk], BF[ni][kk], acc[mi + (MO)][ni + (NO)], 0, 0, 0); \
  __builtin_amdgcn_s_setprio(0); \
} while (0)

  // prologue: stage tiles 0 and 1; wait only for tile 0 (vmcnt(8) leaves
  // tile 1's 8 loads in flight); pre-read tile 0's Q0 operands.
  STAGE_A(0, 0); STAGE_B(0, 0);
  STAGE_A(32768, 64); STAGE_B(32768, 64);
  asm volatile("s_waitcnt vmcnt(8)" ::: "memory");
  PHASE_BAR();
  READ_A1(0); READ_B0(0);

  for (int T = 0; T < NKT; ++T) {
    int cur = (T & 1) * 32768;
    int nxt = 32768 - cur;
    // ph0: Q0 = (mh1, B0); read B1(cur)
    MFMA_Q(a1_, b0_, 4, 0);
    READ_B1(cur);
    PHASE_BAR();
    // ph1: Q1 = (mh1, B1); read A0(cur) — last reads of cur buffer
    MFMA_Q(a1_, b1_, 4, 2);
    READ_A0(cur);
    PHASE_BAR();
    // ph2: Q2 = (mh0, B1); stage tile T+2 into cur (WAR-safe: barrier above)
    MFMA_Q(a0_, b1_, 0, 2);
    if (T <= NKT - 3) { STAGE_A(cur, (T + 2) * 64); STAGE_B(cur, (T + 2) * 64); }
    PHASE_BAR();
    // ph3: Q3 = (mh0, B0) — all operands held, pure MFMA
    MFMA_Q(a0_, b0_, 0, 0);
    if (T < NKT - 1) {
      // need tile T+1 landed; newest 8 loads (tile T+2) may stay in flight
      if (T <= NKT - 3) asm volatile("s_waitcnt vmcnt(8)" ::: "memory");
      else              asm volatile("s_waitcnt vmcnt(0)" ::: "memory");
      PHASE_BAR();
      READ_A1(nxt); READ_B0(nxt);      // tile T+1 Q0 operands
    }
  }

  // epilogue: bias + phi, normal bf16 stores (L2 merges partial lines)
  int rb = g4 * 4;
#pragma unroll
  for (int mi = 0; mi < 8; ++mi) {
#pragma unroll
    for (int ni = 0; ni < 4; ++ni) {
      int col = bcol0 + wc * 64 + ni * 16 + lr;
      float bb = bias[col];
#pragma unroll
      for (int i = 0; i < 4; ++i) {
        size_t row = arow0 + wr * 128 + mi * 16 + rb + i;
        float v = acc[mi][ni][i] + bb;
        if (col < 1536) v = (v > 0.0f) ? (v + 1.0f) : __expf(v);
        C[row * TD_ + col] = f2bf(v);
      }
    }
  }
#undef RDA
#undef RDB
}

// ---------------------------------------------------------------------------
// Attention core, one block per (b,h). Never materializes kv[192][192].
#define ALD 196  // LDS stride for 192-wide bf16 rows

__global__ __launch_bounds__(256) void k_attn(
    const u16* __restrict__ qkv,  // [M_,2304] bf16
    float* __restrict__ mt, float* __restrict__ mi)  // [B_,768] fp32
{
  __shared__ u16 qs[S_ * ALD];
  __shared__ u16 ks2[S_ * ALD];
  __shared__ float z[DH_], wt[S_], wi[S_], qt[DH_], qi[DH_], at[S_], ai[S_];
  int t = threadIdx.x;
  int b = blockIdx.x >> 2, h = blockIdx.x & 3;
  size_t base = (size_t)b * S_ * TD_;
  int qoff = h * DH_, koff = 768 + h * DH_, voff = 1536 + h * DH_;

  for (int idx = t; idx < S_ * 48; idx += 256) {
    int s = idx / 48, c = (idx % 48) * 4;
    *(ushort4*)(&qs[s * ALD + c])  = *(const ushort4*)(&qkv[base + (size_t)s * TD_ + qoff + c]);
    *(ushort4*)(&ks2[s * ALD + c]) = *(const ushort4*)(&qkv[base + (size_t)s * TD_ + koff + c]);
  }
  __syncthreads();
  if (t < DH_) {
    float a = 0;
    for (int s = 0; s < S_; ++s) a += bf2f(ks2[s * ALD + t]);
    z[t] = a;
  }
  __syncthreads();
  if (t < S_) {
    float a = 0;
    for (int d = 0; d < DH_; ++d) a += bf2f(qs[t * ALD + d]) * z[d];
    float den = a + 1e-6f;
    wt[t] = (t < TEXT_) ? 1.0f / (35.0f * den) : 0.0f;
    wi[t] = (t >= TEXT_) ? 1.0f / (36.0f * den) : 0.0f;
  }
  __syncthreads();
  if (t < DH_) {
    float aT = 0, aI = 0;
    for (int s = 0; s < S_; ++s) {
      float qv = bf2f(qs[s * ALD + t]);
      aT += qv * wt[s]; aI += qv * wi[s];
    }
    qt[t] = aT; qi[t] = aI;
  }
  __syncthreads();
  if (t < S_) {
    float aT = 0, aI = 0;
    for (int d = 0; d < DH_; ++d) {
      float kv = bf2f(ks2[t * ALD + d]);
      aT += kv * qt[d]; aI += kv * qi[d];
    }
    at[t] = aT; ai[t] = aI;
  }
  __syncthreads();
  if (t < DH_) {
    float aT = 0, aI = 0;
    for (int s = 0; s < S_; ++s) {
      float vv = bf2f(qkv[base + (size_t)s * TD_ + voff + t]);
      aT += at[s] * vv; aI += ai[s] * vv;
    }
    mt[(size_t)b * D_ + qoff + t] = aT;
    mi[(size_t)b * D_ + qoff + t] = aI;
  }
}

// ---------------------------------------------------------------------------
// Final head: f = m @ w_out^T + b_out ; r = tanh(f) ; cosine similarity.
// GFIN=4: 512 blocks -> 2 waves/SIMD (GFIN=8's 256 blocks was latency-bound).
#define GFIN 4
__global__ __launch_bounds__(256) void k_final(
    const float* __restrict__ mt, const float* __restrict__ mi,
    const float* __restrict__ wT,   // [768,768] = w_out transposed [d][e]
    const float* __restrict__ bout, // [768]
    float* __restrict__ out)        // [B_]
{
  __shared__ float mts[GFIN][768], mis[GFIN][768];
  __shared__ float red[3][4];
  int t = threadIdx.x, b0 = blockIdx.x * GFIN;
  for (int i = t; i < GFIN * 768; i += 256) {
    int g = i / 768, d = i % 768;
    mts[g][d] = mt[(size_t)(b0 + g) * 768 + d];
    mis[g][d] = mi[(size_t)(b0 + g) * 768 + d];
  }
  __syncthreads();
  float aT[GFIN][3] = {}, aI[GFIN][3] = {};
  for (int d = 0; d < 768; ++d) {
    const float* wrow = wT + (size_t)d * 768 + t;
    float w0 = wrow[0], w1 = wrow[256], w2 = wrow[512];
#pragma unroll
    for (int g = 0; g < GFIN; ++g) {
      float m1 = mts[g][d], m2 = mis[g][d];
      aT[g][0] += m1 * w0; aT[g][1] += m1 * w1; aT[g][2] += m1 * w2;
      aI[g][0] += m2 * w0; aI[g][1] += m2 * w1; aI[g][2] += m2 * w2;
    }
  }
  int lane = t & 63, wid = t >> 6;
  for (int g = 0; g < GFIN; ++g) {
    float st = 0, si = 0, sd = 0;
#pragma unroll
    for (int j = 0; j < 3; ++j) {
      float bo = bout[t + j * 256];
      float rt = tanhf(aT[g][j] + bo);
      float ri = tanhf(aI[g][j] + bo);
      st += rt * rt; si += ri * ri; sd += rt * ri;
    }
#pragma unroll
    for (int off = 32; off >= 1; off >>= 1) {
      st += __shfl_down(st, off);
      si += __shfl_down(si, off);
      sd += __shfl_down(sd, off);
    }
    __syncthreads();
    if (lane == 0) { red[0][wid] = st; red[1][wid] = si; red[2][wid] = sd; }
    __syncthreads();
    if (t == 0) {
      float S1 = red[0][0] + red[0][1] + red[0][2] + red[0][3];
      float S2 = red[1][0] + red[1][1] + red[1][2] + red[1][3];
      float S3 = red[2][0] + red[2][1] + red[2][2] + red[2][3];
      out[b0 + g] = S3 / (fmaxf(sqrtf(S1), 1e-8f) * fmaxf(sqrtf(S2), 1e-8f));
    }
  }
}

// ---------------------------------------------------------------------------
extern "C" void kernel_launch(void* const* d_in, const int* in_sizes, int n_in,
                              void* d_out, int out_size, void* d_ws, size_t ws_size,
                              hipStream_t stream) {
  const float* features = (const float*)d_in[0];
  // d_in[1] = attention_mask (unused by forward)
  const float* w_qkv = (const float*)d_in[2];
  const float* b_qkv = (const float*)d_in[3];
  const float* w_out = (const float*)d_in[4];
  const float* b_out = (const float*)d_in[5];
  float* out = (float*)d_out;

  char* ws = (char*)d_ws;
  size_t off = 0;
  auto alloc = [&](size_t bytes) {
    void* p = ws + off;
    off += (bytes + 255) & ~(size_t)255;
    return p;
  };
  u16* qkv  = (u16*)alloc((size_t)M_ * TD_ * 2);   // 670 MB
  u16* Abf  = (u16*)alloc((size_t)M_ * D_ * 2);    // 223 MB
  u16* Wbf  = (u16*)alloc((size_t)TD_ * D_ * 2);   // 3.5 MB
  float* wT = (float*)alloc((size_t)D_ * D_ * 4);  // 2.4 MB
  float* mt = (float*)alloc((size_t)B_ * D_ * 4);  // 6.3 MB
  float* mi = (float*)alloc((size_t)B_ * D_ * 4);  // 6.3 MB
  (void)ws_size;

  hipLaunchKernelGGL(k_cvt_bf16, dim3((M_ * D_ / 8 + 255) / 256), dim3(256), 0, stream,
                     features, Abf, M_ * D_ / 8);
  hipLaunchKernelGGL(k_cvt_bf16, dim3((TD_ * D_ / 8 + 255) / 256), dim3(256), 0, stream,
                     w_qkv, Wbf, TD_ * D_ / 8);
  hipLaunchKernelGGL(k_transpose768, dim3(2304), dim3(256), 0, stream, w_out, wT);

  hipLaunchKernelGGL(k_gemm_qkv, dim3(568 * 9), dim3(512), 0, stream,
                     Abf, Wbf, b_qkv, qkv);
  hipLaunchKernelGGL(k_attn, dim3(B_ * H_), dim3(256), 0, stream, qkv, mt, mi);
  hipLaunchKernelGGL(k_final, dim3(B_ / GFIN), dim3(256), 0, stream, mt, mi, wT, b_out, out);
}

// Round 7
// 1143.934 us; speedup vs baseline: 1.1215x; 1.0043x over previous
//
#include <hip/hip_runtime.h>
#include <hip/hip_bf16.h>

#define B_ 2048
#define S_ 71
#define D_ 768
#define H_ 4
#define DH_ 192
#define TD_ 2304            // 3*D
#define M_ (B_ * S_)        // 145408 = 568*256
#define TEXT_ 35
#define NKT 12              // 768 / 64 K-tiles

typedef unsigned short u16;
typedef unsigned int u32;
typedef __attribute__((ext_vector_type(4))) float f32x4;
typedef __attribute__((ext_vector_type(8))) short bf16x8;

__device__ __forceinline__ u16 f2bf(float f) {
  u32 u = __float_as_uint(f);
  u32 r = (u + 0x7FFFu + ((u >> 16) & 1u)) >> 16;  // RNE
  return (u16)r;
}
__device__ __forceinline__ float bf2f(u16 x) {
  return __uint_as_float(((u32)x) << 16);
}

typedef __attribute__((address_space(1))) const unsigned int GASU;
typedef __attribute__((address_space(3))) unsigned int LASU;
__device__ __forceinline__ void gload16(const void* g, void* l) {
  __builtin_amdgcn_global_load_lds((GASU*)g, (LASU*)l, 16, 0, 0);
}

#define PHASE_BAR() do { __builtin_amdgcn_s_barrier(); asm volatile("" ::: "memory"); } while (0)
#define LGKM0() do { asm volatile("s_waitcnt lgkmcnt(0)" ::: "memory"); __builtin_amdgcn_sched_barrier(0); } while (0)

// ---------------------------------------------------------------------------
// fp32 -> bf16 elementwise, 8 elems/thread, exact grid
__global__ __launch_bounds__(256) void k_cvt_bf16(const float* __restrict__ in,
                                                  u16* __restrict__ out, int n8) {
  int idx = blockIdx.x * 256 + threadIdx.x;
  if (idx >= n8) return;
  const float4* p = (const float4*)(in + (size_t)idx * 8);
  float4 a = p[0], b = p[1];
  uint4 o;
  o.x = (u32)f2bf(a.x) | ((u32)f2bf(a.y) << 16);
  o.y = (u32)f2bf(a.z) | ((u32)f2bf(a.w) << 16);
  o.z = (u32)f2bf(b.x) | ((u32)f2bf(b.y) << 16);
  o.w = (u32)f2bf(b.z) | ((u32)f2bf(b.w) << 16);
  *(uint4*)(out + (size_t)idx * 8) = o;
}

// ---------------------------------------------------------------------------
// w_out [e][d] -> w_outT [d][e]  (768x768 fp32, tiny)
__global__ void k_transpose768(const float* __restrict__ in, float* __restrict__ out) {
  int idx = blockIdx.x * 256 + threadIdx.x;
  int e = idx / 768, d = idx % 768;
  out[(size_t)d * 768 + e] = in[idx];
}

// ---------------------------------------------------------------------------
// GEMM: C[M,2304] = A[M,768](bf16) * Bw[2304,768](bf16 n-major), bias + phi
// epilogue. 256x256 tile, BK=64, 8 waves (2Mx4N), 512 thr, 128 KiB LDS
// (2 K-tile dbuf). m201-faithful 8-phase schedule (4 phases/K-tile, 2
// barriers/phase): each phase = {ds_reads for THIS phase's MFMA; stage
// loads; bar; lgkmcnt(0)+sched_barrier; setprio(1); 16 MFMA; setprio(0);
// bar}. Iter T stages tile T+2 into the CURRENT buffer region-by-region
// after each region's last read (A1@ph1, B@ph2, A0@ph3); counted vmcnt(8)
// once per K-tile at ph3 (drains tile T+1, leaves T+2 in flight).
// chunk^(row&7) 16B XOR swizzle on source+read. Normal C stores.
__global__ __launch_bounds__(512, 2) void k_gemm_qkv(
    const u16* __restrict__ Abf,  // [M_,768] bf16
    const u16* __restrict__ Bw,   // [2304,768] bf16 (n-major)
    const float* __restrict__ bias, // [2304]
    u16* __restrict__ C)            // [M_,2304] bf16, phi on cols<1536
{
  // layout (u16 units): buf*32768 + op*16384 + half*8192 ; half = [128][64]
  __shared__ u16 sm[65536];   // 128 KiB
  int t = threadIdx.x;
  int lane = t & 63, wid = t >> 6;
  int wr = wid >> 2, wc = wid & 3;     // 2 x 4 wave grid
  int lr = lane & 15;
  int g4 = lane >> 4;                  // 0..3 (K granule within kk)

  // XCD-bijective swizzle: nwg = 5112 = 8 * 639; bn inner -> A-panel L2 reuse
  int swz = (blockIdx.x & 7) * 639 + (blockIdx.x >> 3);
  int bm = swz / 9, bn = swz % 9;
  const size_t arow0 = (size_t)bm * 256;
  const int bcol0 = bn * 256;

  // ---- staging descriptors (loop-invariant) --------------------------------
  // chunk ci = w*512 + t -> row = ci>>3, phys granule kg = (ci&7)^(row&7)
  // granule (half, w): w=0 covers rows 0-63 of the half, w=1 rows 64-127.
  int voff[2][2], lba[2][2];
#pragma unroll
  for (int half = 0; half < 2; ++half)
#pragma unroll
    for (int w = 0; w < 2; ++w) {
      int ci = w * 512 + t;
      int row = ci >> 3;
      int kg = (ci & 7) ^ (row & 7);
      voff[half][w] = (half * 128 + row) * 768 + kg * 8;   // u16 units
      lba[half][w] = half * 8192 + w * 4096 + wid * 512;   // wave-uniform LDS base
    }
  const u16* baseA = Abf + arow0 * 768;
  const u16* baseB = Bw + (size_t)bcol0 * 768;

  // A0-region = rows 0-63 of each wave band -> granules (h,w=0)
  // A1-region = rows 64-127 of each band    -> granules (h,w=1)
#define STAGE_A_W(nb, kc, w) do { \
  gload16(baseA + voff[0][w] + (kc), &sm[(nb) + lba[0][w]]); \
  gload16(baseA + voff[1][w] + (kc), &sm[(nb) + lba[1][w]]); \
} while (0)
#define STAGE_B_ALL(nb, kc) do { \
  gload16(baseB + voff[0][0] + (kc), &sm[(nb) + 16384 + lba[0][0]]); \
  gload16(baseB + voff[0][1] + (kc), &sm[(nb) + 16384 + lba[0][1]]); \
  gload16(baseB + voff[1][0] + (kc), &sm[(nb) + 16384 + lba[1][0]]); \
  gload16(baseB + voff[1][1] + (kc), &sm[(nb) + 16384 + lba[1][1]]); \
} while (0)

  // ---- fragment read offsets (swizzled) ------------------------------------
  int gx0 = g4 ^ (lr & 7);             // kk=0 granule; kk=1 -> gx0^4
  int abase = wr * 8192 + lr * 64;                      // + mi*1024 + gsw*8
  int bbase = 16384 + (wc >> 1) * 8192 + (wc & 1) * 4096 + lr * 64; // + ni*1024

  f32x4 acc[8][4] = {};
  bf16x8 a0_[4][2], a1_[4][2], b0_[2][2], b1_[2][2];

#define RDA(bufb, mi, gsw) (*(const bf16x8*)(&sm[(bufb) + abase + (mi) * 1024 + (gsw) * 8]))
#define RDB(bufb, ni, gsw) (*(const bf16x8*)(&sm[(bufb) + bbase + (ni) * 1024 + (gsw) * 8]))
#define READ_A1(bufb) do { \
  _Pragma("unroll") for (int mi = 0; mi < 4; ++mi) { \
    a1_[mi][0] = RDA(bufb, mi + 4, gx0); a1_[mi][1] = RDA(bufb, mi + 4, gx0 ^ 4); } \
} while (0)
#define READ_A0(bufb) do { \
  _Pragma("unroll") for (int mi = 0; mi < 4; ++mi) { \
    a0_[mi][0] = RDA(bufb, mi, gx0); a0_[mi][1] = RDA(bufb, mi, gx0 ^ 4); } \
} while (0)
#define READ_B0(bufb) do { \
  _Pragma("unroll") for (int ni = 0; ni < 2; ++ni) { \
    b0_[ni][0] = RDB(bufb, ni, gx0); b0_[ni][1] = RDB(bufb, ni, gx0 ^ 4); } \
} while (0)
#define READ_B1(bufb) do { \
  _Pragma("unroll") for (int ni = 0; ni < 2; ++ni) { \
    b1_[ni][0] = RDB(bufb, ni + 2, gx0); b1_[ni][1] = RDB(bufb, ni + 2, gx0 ^ 4); } \
} while (0)
#define MFMA_Q(AF, BF, MO, NO) do { \
  __builtin_amdgcn_s_setprio(1); \
  _Pragma("unroll") for (int mi = 0; mi < 4; ++mi) \
  _Pragma("unroll") for (int ni = 0; ni < 2; ++ni) \
  _Pragma("unroll") for (int kk = 0; kk < 2; ++kk) \
    acc[mi + (MO)][ni + (NO)] = __builtin_amdgcn_mfma_f32_16x16x32_bf16( \
        AF[mi][kk], BF[ni][kk], acc[mi + (MO)][ni + (NO)], 0, 0, 0); \
  __builtin_amdgcn_s_setprio(0); \
} while (0)

  // prologue: stage tiles 0 and 1; wait only for tile 0 (vmcnt(8) leaves
  // tile 1's 8 loads in flight).
  STAGE_A_W(0, 0, 0); STAGE_A_W(0, 0, 1); STAGE_B_ALL(0, 0);
  STAGE_A_W(32768, 64, 0); STAGE_A_W(32768, 64, 1); STAGE_B_ALL(32768, 64);
  asm volatile("s_waitcnt vmcnt(8)" ::: "memory");
  PHASE_BAR();

  for (int T = 0; T < NKT; ++T) {
    int cur = (T & 1) * 32768;
    int kc = (T + 2) * 64;
    bool pf = (T <= NKT - 3);
    // ---- ph0: reads A1+B0(cur) [12]; bar; Q0 = (mh1, B0) ----
    READ_A1(cur); READ_B0(cur);
    asm volatile("s_waitcnt lgkmcnt(8)" ::: "memory");   // throttle
    PHASE_BAR();
    LGKM0();
    MFMA_Q(a1_, b0_, 4, 0);
    PHASE_BAR();
    // ---- ph1: read B1(cur) [4]; stage A1-region of T+2 into cur; Q1 ----
    READ_B1(cur);
    if (pf) STAGE_A_W(cur, kc, 1);
    PHASE_BAR();
    LGKM0();
    MFMA_Q(a1_, b1_, 4, 2);
    PHASE_BAR();
    // ---- ph2: read A0(cur) [8]; stage all B of T+2; Q2 ----
    READ_A0(cur);
    if (pf) STAGE_B_ALL(cur, kc);
    PHASE_BAR();
    LGKM0();
    MFMA_Q(a0_, b1_, 0, 2);
    PHASE_BAR();
    // ---- ph3: stage A0-region of T+2; counted vmcnt; Q3 ----
    if (pf) STAGE_A_W(cur, kc, 0);
    if (T <= NKT - 3)      asm volatile("s_waitcnt vmcnt(8)" ::: "memory");
    else if (T == NKT - 2) asm volatile("s_waitcnt vmcnt(0)" ::: "memory");
    PHASE_BAR();
    MFMA_Q(a0_, b0_, 0, 0);
    PHASE_BAR();
  }

  // epilogue: bias + phi, normal bf16 stores (L2 merges partial lines)
  int rb = g4 * 4;
#pragma unroll
  for (int mi = 0; mi < 8; ++mi) {
#pragma unroll
    for (int ni = 0; ni < 4; ++ni) {
      int col = bcol0 + wc * 64 + ni * 16 + lr;
      float bb = bias[col];
#pragma unroll
      for (int i = 0; i < 4; ++i) {
        size_t row = arow0 + wr * 128 + mi * 16 + rb + i;
        float v = acc[mi][ni][i] + bb;
        if (col < 1536) v = (v > 0.0f) ? (v + 1.0f) : __expf(v);
        C[row * TD_ + col] = f2bf(v);
      }
    }
  }
#undef RDA
#undef RDB
}

// ---------------------------------------------------------------------------
// Attention core, one block per (b,h). Never materializes kv[192][192].
#define ALD 196  // LDS stride for 192-wide bf16 rows

__global__ __launch_bounds__(256) void k_attn(
    const u16* __restrict__ qkv,  // [M_,2304] bf16
    float* __restrict__ mt, float* __restrict__ mi)  // [B_,768] fp32
{
  __shared__ u16 qs[S_ * ALD];
  __shared__ u16 ks2[S_ * ALD];
  __shared__ float z[DH_], wt[S_], wi[S_], qt[DH_], qi[DH_], at[S_], ai[S_];
  int t = threadIdx.x;
  int b = blockIdx.x >> 2, h = blockIdx.x & 3;
  size_t base = (size_t)b * S_ * TD_;
  int qoff = h * DH_, koff = 768 + h * DH_, voff = 1536 + h * DH_;

  for (int idx = t; idx < S_ * 48; idx += 256) {
    int s = idx / 48, c = (idx % 48) * 4;
    *(ushort4*)(&qs[s * ALD + c])  = *(const ushort4*)(&qkv[base + (size_t)s * TD_ + qoff + c]);
    *(ushort4*)(&ks2[s * ALD + c]) = *(const ushort4*)(&qkv[base + (size_t)s * TD_ + koff + c]);
  }
  __syncthreads();
  if (t < DH_) {
    float a = 0;
    for (int s = 0; s < S_; ++s) a += bf2f(ks2[s * ALD + t]);
    z[t] = a;
  }
  __syncthreads();
  if (t < S_) {
    float a = 0;
    for (int d = 0; d < DH_; ++d) a += bf2f(qs[t * ALD + d]) * z[d];
    float den = a + 1e-6f;
    wt[t] = (t < TEXT_) ? 1.0f / (35.0f * den) : 0.0f;
    wi[t] = (t >= TEXT_) ? 1.0f / (36.0f * den) : 0.0f;
  }
  __syncthreads();
  if (t < DH_) {
    float aT = 0, aI = 0;
    for (int s = 0; s < S_; ++s) {
      float qv = bf2f(qs[s * ALD + t]);
      aT += qv * wt[s]; aI += qv * wi[s];
    }
    qt[t] = aT; qi[t] = aI;
  }
  __syncthreads();
  if (t < S_) {
    float aT = 0, aI = 0;
    for (int d = 0; d < DH_; ++d) {
      float kv = bf2f(ks2[t * ALD + d]);
      aT += kv * qt[d]; aI += kv * qi[d];
    }
    at[t] = aT; ai[t] = aI;
  }
  __syncthreads();
  if (t < DH_) {
    float aT = 0, aI = 0;
    for (int s = 0; s < S_; ++s) {
      float vv = bf2f(qkv[base + (size_t)s * TD_ + voff + t]);
      aT += at[s] * vv; aI += ai[s] * vv;
    }
    mt[(size_t)b * D_ + qoff + t] = aT;
    mi[(size_t)b * D_ + qoff + t] = aI;
  }
}

// ---------------------------------------------------------------------------
// Final head: f = m @ w_out^T + b_out ; r = tanh(f) ; cosine similarity.
// GFIN=4: 512 blocks -> 2 waves/SIMD (GFIN=8's 256 blocks was latency-bound).
#define GFIN 4
__global__ __launch_bounds__(256) void k_final(
    const float* __restrict__ mt, const float* __restrict__ mi,
    const float* __restrict__ wT,   // [768,768] = w_out transposed [d][e]
    const float* __restrict__ bout, // [768]
    float* __restrict__ out)        // [B_]
{
  __shared__ float mts[GFIN][768], mis[GFIN][768];
  __shared__ float red[3][4];
  int t = threadIdx.x, b0 = blockIdx.x * GFIN;
  for (int i = t; i < GFIN * 768; i += 256) {
    int g = i / 768, d = i % 768;
    mts[g][d] = mt[(size_t)(b0 + g) * 768 + d];
    mis[g][d] = mi[(size_t)(b0 + g) * 768 + d];
  }
  __syncthreads();
  float aT[GFIN][3] = {}, aI[GFIN][3] = {};
  for (int d = 0; d < 768; ++d) {
    const float* wrow = wT + (size_t)d * 768 + t;
    float w0 = wrow[0], w1 = wrow[256], w2 = wrow[512];
#pragma unroll
    for (int g = 0; g < GFIN; ++g) {
      float m1 = mts[g][d], m2 = mis[g][d];
      aT[g][0] += m1 * w0; aT[g][1] += m1 * w1; aT[g][2] += m1 * w2;
      aI[g][0] += m2 * w0; aI[g][1] += m2 * w1; aI[g][2] += m2 * w2;
    }
  }
  int lane = t & 63, wid = t >> 6;
  for (int g = 0; g < GFIN; ++g) {
    float st = 0, si = 0, sd = 0;
#pragma unroll
    for (int j = 0; j < 3; ++j) {
      float bo = bout[t + j * 256];
      float rt = tanhf(aT[g][j] + bo);
      float ri = tanhf(aI[g][j] + bo);
      st += rt * rt; si += ri * ri; sd += rt * ri;
    }
#pragma unroll
    for (int off = 32; off >= 1; off >>= 1) {
      st += __shfl_down(st, off);
      si += __shfl_down(si, off);
      sd += __shfl_down(sd, off);
    }
    __syncthreads();
    if (lane == 0) { red[0][wid] = st; red[1][wid] = si; red[2][wid] = sd; }
    __syncthreads();
    if (t == 0) {
      float S1 = red[0][0] + red[0][1] + red[0][2] + red[0][3];
      float S2 = red[1][0] + red[1][1] + red[1][2] + red[1][3];
      float S3 = red[2][0] + red[2][1] + red[2][2] + red[2][3];
      out[b0 + g] = S3 / (fmaxf(sqrtf(S1), 1e-8f) * fmaxf(sqrtf(S2), 1e-8f));
    }
  }
}

// ---------------------------------------------------------------------------
extern "C" void kernel_launch(void* const* d_in, const int* in_sizes, int n_in,
                              void* d_out, int out_size, void* d_ws, size_t ws_size,
                              hipStream_t stream) {
  const float* features = (const float*)d_in[0];
  // d_in[1] = attention_mask (unused by forward)
  const float* w_qkv = (const float*)d_in[2];
  const float* b_qkv = (const float*)d_in[3];
  const float* w_out = (const float*)d_in[4];
  const float* b_out = (const float*)d_in[5];
  float* out = (float*)d_out;

  char* ws = (char*)d_ws;
  size_t off = 0;
  auto alloc = [&](size_t bytes) {
    void* p = ws + off;
    off += (bytes + 255) & ~(size_t)255;
    return p;
  };
  u16* qkv  = (u16*)alloc((size_t)M_ * TD_ * 2);   // 670 MB
  u16* Abf  = (u16*)alloc((size_t)M_ * D_ * 2);    // 223 MB
  u16* Wbf  = (u16*)alloc((size_t)TD_ * D_ * 2);   // 3.5 MB
  float* wT = (float*)alloc((size_t)D_ * D_ * 4);  // 2.4 MB
  float* mt = (float*)alloc((size_t)B_ * D_ * 4);  // 6.3 MB
  float* mi = (float*)alloc((size_t)B_ * D_ * 4);  // 6.3 MB
  (void)ws_size;

  hipLaunchKernelGGL(k_cvt_bf16, dim3((M_ * D_ / 8 + 255) / 256), dim3(256), 0, stream,
                     features, Abf, M_ * D_ / 8);
  hipLaunchKernelGGL(k_cvt_bf16, dim3((TD_ * D_ / 8 + 255) / 256), dim3(256), 0, stream,
                     w_qkv, Wbf, TD_ * D_ / 8);
  hipLaunchKernelGGL(k_transpose768, dim3(2304), dim3(256), 0, stream, w_out, wT);

  hipLaunchKernelGGL(k_gemm_qkv, dim3(568 * 9), dim3(512), 0, stream,
                     Abf, Wbf, b_qkv, qkv);
  hipLaunchKernelGGL(k_attn, dim3(B_ * H_), dim3(256), 0, stream, qkv, mt, mi);
  hipLaunchKernelGGL(k_final, dim3(B_ / GFIN), dim3(256), 0, stream, mt, mi, wT, b_out, out);
}